// Round 2
// baseline (565.425 us; speedup 1.0000x reference)
//
#include <hip/hip_runtime.h>

// HNN_skip: densify sparse layers -> fp16 MFMA GEMM chain + fused skip/readout.
// Workspace layout (bytes), total 166,723,584 (~159 MB):
//   xh   @ 0          (64MB)  x converted to fp16
//   W1h  @ 67108864   (16MB)  dense W1 fp16 [2048][4096]
//   W2h  @ 83886080   ( 4MB)  dense W2 fp16 [1024][2048]
//   W3h  @ 88080384   ( 1MB)  dense W3 fp16 [ 512][1024]
//   h1h  @ 89128960   (32MB)  relu(x@W1^T+b1) fp16 [8192][2048]
//   Wf1  @ 122683392  (32MB)  fp32 scatter scratch W1; reused: h2h (16MB) + h3h @139460608 (8MB)
//   Wf2  @ 156237824  ( 8MB)  fp32 scatter scratch W2
//   Wf3  @ 164626432  ( 2MB)  fp32 scatter scratch W3

typedef _Float16 f16x8 __attribute__((ext_vector_type(8)));
typedef float f32x4 __attribute__((ext_vector_type(4)));

#define B_SZ 8192
#define L1_SZ 4096
#define L2_SZ 2048
#define L3_SZ 1024
#define L4_SZ 512
#define NNZ1_SZ 262144
#define NNZ2_SZ 131072
#define NNZ3_SZ 65536
#define ND2_SZ 256
#define ND3_SZ 128

__global__ void k_f32_to_f16(const float* __restrict__ src, _Float16* __restrict__ dst, int n) {
  int i = (blockIdx.x * blockDim.x + threadIdx.x) * 8;
  if (i >= n) return;
  const float4 v0 = *reinterpret_cast<const float4*>(src + i);
  const float4 v1 = *reinterpret_cast<const float4*>(src + i + 4);
  f16x8 o;
  o[0] = (_Float16)v0.x; o[1] = (_Float16)v0.y;
  o[2] = (_Float16)v0.z; o[3] = (_Float16)v0.w;
  o[4] = (_Float16)v1.x; o[5] = (_Float16)v1.y;
  o[6] = (_Float16)v1.z; o[7] = (_Float16)v1.w;
  *reinterpret_cast<f16x8*>(dst + i) = o;
}

__global__ void k_scatter(const int* __restrict__ ein, const int* __restrict__ eout,
                          const float* __restrict__ w, int nnz, float* __restrict__ Wf, int K) {
  int e = blockIdx.x * blockDim.x + threadIdx.x;
  if (e < nnz) atomicAdd(Wf + (size_t)eout[e] * K + ein[e], w[e]);
}

__device__ __forceinline__ void gload_lds16(const _Float16* g, _Float16* l) {
  __builtin_amdgcn_global_load_lds((const __attribute__((address_space(1))) void*)g,
                                   (__attribute__((address_space(3))) void*)l, 16, 0, 0);
}

// C[M,N] = relu(A[M,K] @ Bt[N,K]^T + bias[N]); fp16 in/out, fp32 accumulate.
// m97-style: 128x128 tile, BK=32, 4 waves (2x2), 4x4 mfma_f32_16x16x32_f16 per wave.
// LDS swizzle (rule #21): linear LDS dest for global_load_lds, source chunk
// pre-swizzled with c ^= (row>>1)&3, identical swizzle on ds_read addresses
// -> every 16-lane fragment group covers all 32 banks 2-way (free).
__global__ __launch_bounds__(256) void gemm_bt_f16(
    const _Float16* __restrict__ A, const _Float16* __restrict__ Bt,
    const float* __restrict__ bias, _Float16* __restrict__ C,
    int M, int N, int K)
{
  __shared__ alignas(16) _Float16 As[128 * 32];
  __shared__ alignas(16) _Float16 Bs[128 * 32];
  const int t = threadIdx.x;
  const int lane = t & 63;
  const int wv = t >> 6;
  const int wm = wv >> 1, wn = wv & 1;
  const int m0 = blockIdx.x * 128, n0 = blockIdx.y * 128;

  // staging: thread t owns 16B chunk (row = t/4, chunk = t%4); 2 halves each for A,B
  const int srow = t >> 2;
  const int sc = (t & 3) ^ ((srow >> 1) & 3);
  const _Float16* Ag0 = A + (size_t)(m0 + srow) * K + sc * 8;
  const _Float16* Ag1 = A + (size_t)(m0 + 64 + srow) * K + sc * 8;   // ((srow+64)>>1)&3 == (srow>>1)&3
  const _Float16* Bg0 = Bt + (size_t)(n0 + srow) * K + sc * 8;
  const _Float16* Bg1 = Bt + (size_t)(n0 + 64 + srow) * K + sc * 8;
  _Float16* lA0 = As + t * 8;
  _Float16* lA1 = As + 2048 + t * 8;
  _Float16* lB0 = Bs + t * 8;
  _Float16* lB1 = Bs + 2048 + t * 8;

  const int rl = lane & 15;      // fragment row/col within 16
  const int koff = lane >> 4;    // k-chunk 0..3 (8 halves each)

  f32x4 acc[4][4] = {};

  for (int kt = 0; kt < K; kt += 32) {
    gload_lds16(Ag0 + kt, lA0);
    gload_lds16(Ag1 + kt, lA1);
    gload_lds16(Bg0 + kt, lB0);
    gload_lds16(Bg1 + kt, lB1);
    __syncthreads();   // compiler emits vmcnt(0) drain before s_barrier

    f16x8 af[4], bf[4];
#pragma unroll
    for (int i = 0; i < 4; ++i) {
      const int ra = wm * 64 + i * 16 + rl;
      const int ca = koff ^ ((ra >> 1) & 3);
      af[i] = *reinterpret_cast<const f16x8*>(As + ra * 32 + ca * 8);
      const int rb = wn * 64 + i * 16 + rl;
      const int cb = koff ^ ((rb >> 1) & 3);
      bf[i] = *reinterpret_cast<const f16x8*>(Bs + rb * 32 + cb * 8);
    }
#pragma unroll
    for (int i = 0; i < 4; ++i)
#pragma unroll
      for (int j = 0; j < 4; ++j)
        acc[i][j] = __builtin_amdgcn_mfma_f32_16x16x32_f16(af[i], bf[j], acc[i][j], 0, 0, 0);
    __syncthreads();
  }

  // epilogue: bias + relu + fp16 store. C/D layout (m89): col=lane&15, row=(lane>>4)*4+reg
#pragma unroll
  for (int j = 0; j < 4; ++j) {
    const int col = n0 + wn * 64 + j * 16 + rl;
    const float bj = bias[col];
#pragma unroll
    for (int i = 0; i < 4; ++i) {
      const int row = m0 + wm * 64 + i * 16 + koff * 4;
#pragma unroll
      for (int r = 0; r < 4; ++r) {
        float v = acc[i][j][r] + bj;
        v = v > 0.f ? v : 0.f;
        C[(size_t)(row + r) * N + col] = (_Float16)v;
      }
    }
  }
}

// One wave per batch row: sk2, sk3, f4 partial dots + shuffle-reduce + readout.
__global__ __launch_bounds__(256) void k_final(
    const _Float16* __restrict__ h1, const _Float16* __restrict__ h2,
    const _Float16* __restrict__ h3,
    const int* __restrict__ d2, const float* __restrict__ wsk2, const float* __restrict__ bsk2,
    const int* __restrict__ d3, const float* __restrict__ wsk3, const float* __restrict__ bsk3,
    const float* __restrict__ W4, const float* __restrict__ b4,
    const float* __restrict__ Wro, const float* __restrict__ bro,
    float* __restrict__ out)
{
  const int gtid = blockIdx.x * 256 + threadIdx.x;
  const int b = gtid >> 6;
  const int lane = gtid & 63;
  const _Float16* r1 = h1 + (size_t)b * L2_SZ;
  const _Float16* r2 = h2 + (size_t)b * L3_SZ;
  const _Float16* r3 = h3 + (size_t)b * L4_SZ;
  float s2 = 0.f, s3 = 0.f, s4 = 0.f;
#pragma unroll
  for (int j = lane; j < ND2_SZ; j += 64) s2 += (float)r1[d2[j]] * wsk2[j];
#pragma unroll
  for (int j = lane; j < ND3_SZ; j += 64) s3 += (float)r2[d3[j]] * wsk3[j];
#pragma unroll
  for (int j = lane; j < L4_SZ; j += 64) s4 += (float)r3[j] * W4[j];
#pragma unroll
  for (int off = 32; off > 0; off >>= 1) {
    s2 += __shfl_xor(s2, off);
    s3 += __shfl_xor(s3, off);
    s4 += __shfl_xor(s4, off);
  }
  if (lane == 0) {
    const float v2 = fmaxf(s2 + bsk2[0], 0.f);
    const float v3 = fmaxf(s3 + bsk3[0], 0.f);
    const float v4 = fmaxf(s4 + b4[0], 0.f);
    out[b] = Wro[0] * v2 + Wro[1] * v3 + Wro[2] * v4 + bro[0];
  }
}

extern "C" void kernel_launch(void* const* d_in, const int* in_sizes, int n_in,
                              void* d_out, int out_size, void* d_ws, size_t ws_size,
                              hipStream_t stream) {
  const float* x    = (const float*)d_in[0];
  const int* in1    = (const int*)d_in[1];
  const int* out1   = (const int*)d_in[2];
  const float* w1   = (const float*)d_in[3];
  const float* b1   = (const float*)d_in[4];
  const int* in2    = (const int*)d_in[5];
  const int* out2   = (const int*)d_in[6];
  const float* w2   = (const float*)d_in[7];
  const float* b2   = (const float*)d_in[8];
  const int* d2     = (const int*)d_in[9];
  const float* wsk2 = (const float*)d_in[10];
  const float* bsk2 = (const float*)d_in[11];
  const int* in3    = (const int*)d_in[12];
  const int* out3   = (const int*)d_in[13];
  const float* w3   = (const float*)d_in[14];
  const float* b3   = (const float*)d_in[15];
  const int* d3     = (const int*)d_in[16];
  const float* wsk3 = (const float*)d_in[17];
  const float* bsk3 = (const float*)d_in[18];
  const float* W4   = (const float*)d_in[19];
  const float* b4   = (const float*)d_in[20];
  const float* Wro  = (const float*)d_in[21];
  const float* bro  = (const float*)d_in[22];
  float* out = (float*)d_out;

  char* ws = (char*)d_ws;
  _Float16* xh  = (_Float16*)(ws + 0);
  _Float16* W1h = (_Float16*)(ws + 67108864);
  _Float16* W2h = (_Float16*)(ws + 83886080);
  _Float16* W3h = (_Float16*)(ws + 88080384);
  _Float16* h1h = (_Float16*)(ws + 89128960);
  float*    Wf1 = (float*)   (ws + 122683392);
  _Float16* h2h = (_Float16*)(ws + 122683392);   // reuses Wf1 region after W1 convert
  _Float16* h3h = (_Float16*)(ws + 139460608);   // reuses Wf1 region after W1 convert
  float*    Wf2 = (float*)   (ws + 156237824);
  float*    Wf3 = (float*)   (ws + 164626432);

  // zero all three fp32 scatter scratches (contiguous 42MB)
  hipMemsetAsync(ws + 122683392, 0, 44040192, stream);

  // x -> fp16
  k_f32_to_f16<<<(B_SZ * L1_SZ / 8 + 255) / 256, 256, 0, stream>>>(x, xh, B_SZ * L1_SZ);

  // densify sparse weights (fp32 atomics handle duplicate edges), then convert fp16
  k_scatter<<<(NNZ1_SZ + 255) / 256, 256, 0, stream>>>(in1, out1, w1, NNZ1_SZ, Wf1, L1_SZ);
  k_scatter<<<(NNZ2_SZ + 255) / 256, 256, 0, stream>>>(in2, out2, w2, NNZ2_SZ, Wf2, L2_SZ);
  k_scatter<<<(NNZ3_SZ + 255) / 256, 256, 0, stream>>>(in3, out3, w3, NNZ3_SZ, Wf3, L3_SZ);
  k_f32_to_f16<<<(L2_SZ * L1_SZ / 8 + 255) / 256, 256, 0, stream>>>(Wf1, W1h, L2_SZ * L1_SZ);
  k_f32_to_f16<<<(L3_SZ * L2_SZ / 8 + 255) / 256, 256, 0, stream>>>(Wf2, W2h, L3_SZ * L2_SZ);
  k_f32_to_f16<<<(L4_SZ * L3_SZ / 8 + 255) / 256, 256, 0, stream>>>(Wf3, W3h, L4_SZ * L3_SZ);

  // GEMM chain: h1 = relu(x@W1^T+b1); h2 = relu(h1@W2^T+b2); h3 = relu(h2@W3^T+b3)
  gemm_bt_f16<<<dim3(B_SZ / 128, L2_SZ / 128), 256, 0, stream>>>(xh, W1h, b1, h1h, B_SZ, L2_SZ, L1_SZ);
  gemm_bt_f16<<<dim3(B_SZ / 128, L3_SZ / 128), 256, 0, stream>>>(h1h, W2h, b2, h2h, B_SZ, L3_SZ, L2_SZ);
  gemm_bt_f16<<<dim3(B_SZ / 128, L4_SZ / 128), 256, 0, stream>>>(h2h, W3h, b3, h3h, B_SZ, L4_SZ, L3_SZ);

  // skips + fc4 + readout
  k_final<<<B_SZ * 64 / 256, 256, 0, stream>>>(h1h, h2h, h3h, d2, wsk2, bsk2,
                                               d3, wsk3, bsk3, W4, b4, Wro, bro, out);
}

// Round 3
// 503.432 us; speedup vs baseline: 1.1231x; 1.1231x over previous
//
#include <hip/hip_runtime.h>

// HNN_skip: densify sparse layers -> fp16 MFMA GEMM chain + fused skip/readout.
// R2 change: GEMM K-loop restructured from single-buffer/2-barrier (latency-bound,
// MfmaUtil 25%) to 3-buffer depth-2 pipeline with counted vmcnt(4) + raw s_barrier
// (T3+T4 minimum form) + setprio(1) around MFMA (T5).
//
// Workspace layout (bytes), total 166,723,584 (~159 MB):
//   xh   @ 0          (64MB)  x converted to fp16
//   W1h  @ 67108864   (16MB)  dense W1 fp16 [2048][4096]
//   W2h  @ 83886080   ( 4MB)  dense W2 fp16 [1024][2048]
//   W3h  @ 88080384   ( 1MB)  dense W3 fp16 [ 512][1024]
//   h1h  @ 89128960   (32MB)  relu(x@W1^T+b1) fp16 [8192][2048]
//   Wf1  @ 122683392  (32MB)  fp32 scatter scratch W1; reused: h2h (16MB) + h3h @139460608 (8MB)
//   Wf2  @ 156237824  ( 8MB)  fp32 scatter scratch W2
//   Wf3  @ 164626432  ( 2MB)  fp32 scatter scratch W3

typedef _Float16 f16x8 __attribute__((ext_vector_type(8)));
typedef float f32x4 __attribute__((ext_vector_type(4)));

#define B_SZ 8192
#define L1_SZ 4096
#define L2_SZ 2048
#define L3_SZ 1024
#define L4_SZ 512
#define NNZ1_SZ 262144
#define NNZ2_SZ 131072
#define NNZ3_SZ 65536
#define ND2_SZ 256
#define ND3_SZ 128

__global__ void k_f32_to_f16(const float* __restrict__ src, _Float16* __restrict__ dst, int n) {
  int i = (blockIdx.x * blockDim.x + threadIdx.x) * 8;
  if (i >= n) return;
  const float4 v0 = *reinterpret_cast<const float4*>(src + i);
  const float4 v1 = *reinterpret_cast<const float4*>(src + i + 4);
  f16x8 o;
  o[0] = (_Float16)v0.x; o[1] = (_Float16)v0.y;
  o[2] = (_Float16)v0.z; o[3] = (_Float16)v0.w;
  o[4] = (_Float16)v1.x; o[5] = (_Float16)v1.y;
  o[6] = (_Float16)v1.z; o[7] = (_Float16)v1.w;
  *reinterpret_cast<f16x8*>(dst + i) = o;
}

__global__ void k_scatter(const int* __restrict__ ein, const int* __restrict__ eout,
                          const float* __restrict__ w, int nnz, float* __restrict__ Wf, int K) {
  int e = blockIdx.x * blockDim.x + threadIdx.x;
  if (e < nnz) atomicAdd(Wf + (size_t)eout[e] * K + ein[e], w[e]);
}

__device__ __forceinline__ void gload_lds16(const _Float16* g, _Float16* l) {
  __builtin_amdgcn_global_load_lds((const __attribute__((address_space(1))) void*)g,
                                   (__attribute__((address_space(3))) void*)l, 16, 0, 0);
}

// C[M,N] = relu(A[M,K] @ Bt[N,K]^T + bias[N]); fp16 in/out, fp32 accumulate.
// 128x128 tile, BK=32, 4 waves (2x2), 4x4 mfma_f32_16x16x32_f16 per wave.
// Pipeline: 3 LDS buffers (48KB), depth-2 lookahead, counted vmcnt(4),
// raw s_barrier (no implicit vmcnt(0) drain), one barrier per K-step.
// Safety: buffer staged at iter t is read at t+2 (vmcnt(4)+barrier at t+1
// guarantees arrival); buffer read at t is re-staged at t+3 (two barriers
// after last ds_read, which completed before that iter's MFMA via compiler
// lgkmcnt). Barriers control-uniform.
// LDS swizzle (rule #21): linear LDS dest for global_load_lds, source chunk
// pre-swizzled with c ^= (row>>1)&3, identical swizzle on ds_read addresses.
__global__ __launch_bounds__(256) void gemm_bt_f16(
    const _Float16* __restrict__ A, const _Float16* __restrict__ Bt,
    const float* __restrict__ bias, _Float16* __restrict__ C,
    int M, int N, int K)
{
  __shared__ alignas(16) _Float16 lds[3 * 8192];   // per buf: A halves [0,4096), B halves [4096,8192)
  const int t = threadIdx.x;
  const int lane = t & 63;
  const int wv = t >> 6;
  const int wm = wv >> 1, wn = wv & 1;
  const int m0 = blockIdx.x * 128, n0 = blockIdx.y * 128;

  // staging: thread t owns 16B chunk (row = t/4, chunk = t%4); 2 halves each for A,B
  const int srow = t >> 2;
  const int sc = (t & 3) ^ ((srow >> 1) & 3);
  const _Float16* Ag0 = A + (size_t)(m0 + srow) * K + sc * 8;
  const _Float16* Ag1 = A + (size_t)(m0 + 64 + srow) * K + sc * 8;   // ((srow+64)>>1)&3 == (srow>>1)&3
  const _Float16* Bg0 = Bt + (size_t)(n0 + srow) * K + sc * 8;
  const _Float16* Bg1 = Bt + (size_t)(n0 + 64 + srow) * K + sc * 8;
  const int sA0 = t * 8, sA1 = 2048 + t * 8;
  const int sB0 = 4096 + t * 8, sB1 = 6144 + t * 8;

  const int rl = lane & 15;      // fragment row/col within 16
  const int koff = lane >> 4;    // k-chunk 0..3 (8 halves each)

  f32x4 acc[4][4] = {};

  auto STAGE = [&](int bufo, int kt) {
    gload_lds16(Ag0 + kt, lds + bufo + sA0);
    gload_lds16(Ag1 + kt, lds + bufo + sA1);
    gload_lds16(Bg0 + kt, lds + bufo + sB0);
    gload_lds16(Bg1 + kt, lds + bufo + sB1);
  };

  auto COMPUTE = [&](int bufo) {
    f16x8 af[4], bf[4];
#pragma unroll
    for (int i = 0; i < 4; ++i) {
      const int ra = wm * 64 + i * 16 + rl;
      const int ca = koff ^ ((ra >> 1) & 3);
      af[i] = *reinterpret_cast<const f16x8*>(lds + bufo + ra * 32 + ca * 8);
      const int rb = wn * 64 + i * 16 + rl;
      const int cb = koff ^ ((rb >> 1) & 3);
      bf[i] = *reinterpret_cast<const f16x8*>(lds + bufo + 4096 + rb * 32 + cb * 8);
    }
    __builtin_amdgcn_s_setprio(1);
#pragma unroll
    for (int i = 0; i < 4; ++i)
#pragma unroll
      for (int j = 0; j < 4; ++j)
        acc[i][j] = __builtin_amdgcn_mfma_f32_16x16x32_f16(af[i], bf[j], acc[i][j], 0, 0, 0);
    __builtin_amdgcn_s_setprio(0);
  };

  int b0 = 0, b1 = 8192, b2 = 16384;
  // prologue: fill depth-2 pipeline
  STAGE(b0, 0);
  STAGE(b1, 32);
  asm volatile("s_waitcnt vmcnt(4)" ::: "memory");   // b0 staged (b1's 4 may be in flight)
  __builtin_amdgcn_s_barrier();

  const int nt = K / 32;                             // >= 32 for all three GEMMs
  int kst = 64;
  for (int tt = 0; tt < nt - 2; ++tt) {
    STAGE(b2, kst); kst += 32;                       // issue t+2 before compute (overlap)
    COMPUTE(b0);
    asm volatile("s_waitcnt vmcnt(4)" ::: "memory"); // t+1's loads landed; t+2's stay in flight
    __builtin_amdgcn_s_barrier();
    const int tmp = b0; b0 = b1; b1 = b2; b2 = tmp;
  }
  // epilogue of pipeline: last two tiles, no further staging
  COMPUTE(b0);
  asm volatile("s_waitcnt vmcnt(0)" ::: "memory");
  __builtin_amdgcn_s_barrier();
  COMPUTE(b1);

  // epilogue: bias + relu + fp16 store. C/D layout (m89): col=lane&15, row=(lane>>4)*4+reg
#pragma unroll
  for (int j = 0; j < 4; ++j) {
    const int col = n0 + wn * 64 + j * 16 + rl;
    const float bj = bias[col];
#pragma unroll
    for (int i = 0; i < 4; ++i) {
      const int row = m0 + wm * 64 + i * 16 + koff * 4;
#pragma unroll
      for (int r = 0; r < 4; ++r) {
        float v = acc[i][j][r] + bj;
        v = v > 0.f ? v : 0.f;
        C[(size_t)(row + r) * N + col] = (_Float16)v;
      }
    }
  }
}

// One wave per batch row: sk2, sk3, f4 partial dots + shuffle-reduce + readout.
__global__ __launch_bounds__(256) void k_final(
    const _Float16* __restrict__ h1, const _Float16* __restrict__ h2,
    const _Float16* __restrict__ h3,
    const int* __restrict__ d2, const float* __restrict__ wsk2, const float* __restrict__ bsk2,
    const int* __restrict__ d3, const float* __restrict__ wsk3, const float* __restrict__ bsk3,
    const float* __restrict__ W4, const float* __restrict__ b4,
    const float* __restrict__ Wro, const float* __restrict__ bro,
    float* __restrict__ out)
{
  const int gtid = blockIdx.x * 256 + threadIdx.x;
  const int b = gtid >> 6;
  const int lane = gtid & 63;
  const _Float16* r1 = h1 + (size_t)b * L2_SZ;
  const _Float16* r2 = h2 + (size_t)b * L3_SZ;
  const _Float16* r3 = h3 + (size_t)b * L4_SZ;
  float s2 = 0.f, s3 = 0.f, s4 = 0.f;
#pragma unroll
  for (int j = lane; j < ND2_SZ; j += 64) s2 += (float)r1[d2[j]] * wsk2[j];
#pragma unroll
  for (int j = lane; j < ND3_SZ; j += 64) s3 += (float)r2[d3[j]] * wsk3[j];
#pragma unroll
  for (int j = lane; j < L4_SZ; j += 64) s4 += (float)r3[j] * W4[j];
#pragma unroll
  for (int off = 32; off > 0; off >>= 1) {
    s2 += __shfl_xor(s2, off);
    s3 += __shfl_xor(s3, off);
    s4 += __shfl_xor(s4, off);
  }
  if (lane == 0) {
    const float v2 = fmaxf(s2 + bsk2[0], 0.f);
    const float v3 = fmaxf(s3 + bsk3[0], 0.f);
    const float v4 = fmaxf(s4 + b4[0], 0.f);
    out[b] = Wro[0] * v2 + Wro[1] * v3 + Wro[2] * v4 + bro[0];
  }
}

extern "C" void kernel_launch(void* const* d_in, const int* in_sizes, int n_in,
                              void* d_out, int out_size, void* d_ws, size_t ws_size,
                              hipStream_t stream) {
  const float* x    = (const float*)d_in[0];
  const int* in1    = (const int*)d_in[1];
  const int* out1   = (const int*)d_in[2];
  const float* w1   = (const float*)d_in[3];
  const float* b1   = (const float*)d_in[4];
  const int* in2    = (const int*)d_in[5];
  const int* out2   = (const int*)d_in[6];
  const float* w2   = (const float*)d_in[7];
  const float* b2   = (const float*)d_in[8];
  const int* d2     = (const int*)d_in[9];
  const float* wsk2 = (const float*)d_in[10];
  const float* bsk2 = (const float*)d_in[11];
  const int* in3    = (const int*)d_in[12];
  const int* out3   = (const int*)d_in[13];
  const float* w3   = (const float*)d_in[14];
  const float* b3   = (const float*)d_in[15];
  const int* d3     = (const int*)d_in[16];
  const float* wsk3 = (const float*)d_in[17];
  const float* bsk3 = (const float*)d_in[18];
  const float* W4   = (const float*)d_in[19];
  const float* b4   = (const float*)d_in[20];
  const float* Wro  = (const float*)d_in[21];
  const float* bro  = (const float*)d_in[22];
  float* out = (float*)d_out;

  char* ws = (char*)d_ws;
  _Float16* xh  = (_Float16*)(ws + 0);
  _Float16* W1h = (_Float16*)(ws + 67108864);
  _Float16* W2h = (_Float16*)(ws + 83886080);
  _Float16* W3h = (_Float16*)(ws + 88080384);
  _Float16* h1h = (_Float16*)(ws + 89128960);
  float*    Wf1 = (float*)   (ws + 122683392);
  _Float16* h2h = (_Float16*)(ws + 122683392);   // reuses Wf1 region after W1 convert
  _Float16* h3h = (_Float16*)(ws + 139460608);   // reuses Wf1 region after W1 convert
  float*    Wf2 = (float*)   (ws + 156237824);
  float*    Wf3 = (float*)   (ws + 164626432);

  // zero all three fp32 scatter scratches (contiguous 42MB)
  hipMemsetAsync(ws + 122683392, 0, 44040192, stream);

  // x -> fp16
  k_f32_to_f16<<<(B_SZ * L1_SZ / 8 + 255) / 256, 256, 0, stream>>>(x, xh, B_SZ * L1_SZ);

  // densify sparse weights (fp32 atomics handle duplicate edges), then convert fp16
  k_scatter<<<(NNZ1_SZ + 255) / 256, 256, 0, stream>>>(in1, out1, w1, NNZ1_SZ, Wf1, L1_SZ);
  k_scatter<<<(NNZ2_SZ + 255) / 256, 256, 0, stream>>>(in2, out2, w2, NNZ2_SZ, Wf2, L2_SZ);
  k_scatter<<<(NNZ3_SZ + 255) / 256, 256, 0, stream>>>(in3, out3, w3, NNZ3_SZ, Wf3, L3_SZ);
  k_f32_to_f16<<<(L2_SZ * L1_SZ / 8 + 255) / 256, 256, 0, stream>>>(Wf1, W1h, L2_SZ * L1_SZ);
  k_f32_to_f16<<<(L3_SZ * L2_SZ / 8 + 255) / 256, 256, 0, stream>>>(Wf2, W2h, L3_SZ * L2_SZ);
  k_f32_to_f16<<<(L4_SZ * L3_SZ / 8 + 255) / 256, 256, 0, stream>>>(Wf3, W3h, L4_SZ * L3_SZ);

  // GEMM chain: h1 = relu(x@W1^T+b1); h2 = relu(h1@W2^T+b2); h3 = relu(h2@W3^T+b3)
  gemm_bt_f16<<<dim3(B_SZ / 128, L2_SZ / 128), 256, 0, stream>>>(xh, W1h, b1, h1h, B_SZ, L2_SZ, L1_SZ);
  gemm_bt_f16<<<dim3(B_SZ / 128, L3_SZ / 128), 256, 0, stream>>>(h1h, W2h, b2, h2h, B_SZ, L3_SZ, L2_SZ);
  gemm_bt_f16<<<dim3(B_SZ / 128, L4_SZ / 128), 256, 0, stream>>>(h2h, W3h, b3, h3h, B_SZ, L4_SZ, L3_SZ);

  // skips + fc4 + readout
  k_final<<<B_SZ * 64 / 256, 256, 0, stream>>>(h1h, h2h, h3h, d2, wsk2, bsk2,
                                               d3, wsk3, bsk3, W4, b4, Wro, bro, out);
}

// Round 8
// 487.443 us; speedup vs baseline: 1.1600x; 1.0328x over previous
//
#include <hip/hip_runtime.h>

// HNN_skip: densify sparse layers -> fp16 MFMA GEMM chain + fused skip/readout.
// R8 = resubmit of R4..R7 (four GPU acquisition timeouts; kernel never ran).
// Desk-checked 3x (geometry, WAR/RAW vmcnt ledger, rule-#21 swizzle, m89 C/D).
// R4: GEMM1 ported to 256x256/BK=64 8-phase schedule (T2+T3+T4+T5 + T1 XCD swizzle).
//     GEMM2/3 keep the R3 128x128 depth-2 pipeline (proven, adequate for their size).
//
// Workspace layout (bytes), total 166,723,584 (~159 MB):
//   xh   @ 0          (64MB)  x converted to fp16
//   W1h  @ 67108864   (16MB)  dense W1 fp16 [2048][4096]
//   W2h  @ 83886080   ( 4MB)  dense W2 fp16 [1024][2048]
//   W3h  @ 88080384   ( 1MB)  dense W3 fp16 [ 512][1024]
//   h1h  @ 89128960   (32MB)  relu(x@W1^T+b1) fp16 [8192][2048]
//   Wf1  @ 122683392  (32MB)  fp32 scatter scratch W1; reused: h2h (16MB) + h3h @139460608 (8MB)
//   Wf2  @ 156237824  ( 8MB)  fp32 scatter scratch W2
//   Wf3  @ 164626432  ( 2MB)  fp32 scatter scratch W3

typedef _Float16 f16x8 __attribute__((ext_vector_type(8)));
typedef float f32x4 __attribute__((ext_vector_type(4)));

#define B_SZ 8192
#define L1_SZ 4096
#define L2_SZ 2048
#define L3_SZ 1024
#define L4_SZ 512
#define NNZ1_SZ 262144
#define NNZ2_SZ 131072
#define NNZ3_SZ 65536
#define ND2_SZ 256
#define ND3_SZ 128

__global__ void k_f32_to_f16(const float* __restrict__ src, _Float16* __restrict__ dst, int n) {
  int i = (blockIdx.x * blockDim.x + threadIdx.x) * 8;
  if (i >= n) return;
  const float4 v0 = *reinterpret_cast<const float4*>(src + i);
  const float4 v1 = *reinterpret_cast<const float4*>(src + i + 4);
  f16x8 o;
  o[0] = (_Float16)v0.x; o[1] = (_Float16)v0.y;
  o[2] = (_Float16)v0.z; o[3] = (_Float16)v0.w;
  o[4] = (_Float16)v1.x; o[5] = (_Float16)v1.y;
  o[6] = (_Float16)v1.z; o[7] = (_Float16)v1.w;
  *reinterpret_cast<f16x8*>(dst + i) = o;
}

__global__ void k_scatter(const int* __restrict__ ein, const int* __restrict__ eout,
                          const float* __restrict__ w, int nnz, float* __restrict__ Wf, int K) {
  int e = blockIdx.x * blockDim.x + threadIdx.x;
  if (e < nnz) atomicAdd(Wf + (size_t)eout[e] * K + ein[e], w[e]);
}

__device__ __forceinline__ void gload_lds16(const _Float16* g, _Float16* l) {
  __builtin_amdgcn_global_load_lds((const __attribute__((address_space(1))) void*)g,
                                   (__attribute__((address_space(3))) void*)l, 16, 0, 0);
}

// ---------------------------------------------------------------------------
// 256x256 8-phase GEMM (GEMM1): C = relu(A[M,K] @ Bt[N,K]^T + bias), fp16/fp32acc.
// 8 waves (wm=wv>>2 in {0,1}, wn=wv&3 in {0..3}); per-wave 8x4 fragments.
// Wave rows:  wm*64 + (fr&3)*16 + (fr>>2)*128  -> fr 0-3 in A-half0, 4-7 in A-half1.
// Wave cols:  wn*32 + (fc&1)*16 + (fc>>1)*128  -> fc 0,1 in B-half0, 2,3 in B-half1.
// Phase (rh,ch) reads ONLY A-half(rh)+B-half(ch): 8+4 ds_read_b128, 16 MFMA.
// Stage schedule (window k): ph1 -> (k+1).A1, ph2 -> (k+1).B1, ph3 -> (k+2).A0,
// ph4 -> (k+2).B0; every region staged strictly AFTER its last read + barrier.
// vmcnt(4) once per window (2 half-tiles in flight); vmcnt(0) at window nt-2.
// LDS swizzle: chunk ^= (row>>1)&7 (2-way banks = free, m136); pre-swizzled
// global source + linear gload_lds dest + same XOR on ds_read (rule #21).
// ---------------------------------------------------------------------------
__global__ __launch_bounds__(512, 2) void gemm256_f16(
    const _Float16* __restrict__ A, const _Float16* __restrict__ Bt,
    const float* __restrict__ bias, _Float16* __restrict__ C,
    int M, int N, int K)
{
  __shared__ alignas(16) _Float16 Asl[2][16384];   // 2 buf x 256 rows x 64 fp16 = 64KB
  __shared__ alignas(16) _Float16 Bsl[2][16384];   // 64KB
  const int t = threadIdx.x;
  const int lane = t & 63;
  const int wv = t >> 6;
  const int wm = wv >> 2, wn = wv & 3;

  // T1: XCD-aware swizzle — each XCD keeps one contiguous chunk (B-panel L2-pinned)
  const int nwgx = gridDim.x;
  const int wg = blockIdx.x + nwgx * blockIdx.y;
  const int nwg = nwgx * gridDim.y;            // must be divisible by 8
  const int swz = (wg & 7) * (nwg >> 3) + (wg >> 3);
  const int m0 = (swz % nwgx) * 256;
  const int n0 = (swz / nwgx) * 256;

  // staging: thread t owns 16B chunk; row-within-64 = t>>3, source chunk pre-swizzled
  const int srow = t >> 3;
  const int scol = ((t & 7) ^ ((t >> 4) & 7)) * 8;
  const size_t sK = (size_t)K;

  const int rl = lane & 15;
  const int koff = lane >> 4;

  f32x4 acc[8][4] = {};

  auto STAGE_A = [&](int buf, int h, int kt) {
    const _Float16* g = A + (size_t)(m0 + h * 128 + srow) * sK + kt * 64 + scol;
    _Float16* d = &Asl[buf][h * 8192 + t * 8];
    gload_lds16(g, d);
    gload_lds16(g + 64 * sK, d + 4096);
  };
  auto STAGE_B = [&](int buf, int h, int kt) {
    const _Float16* g = Bt + (size_t)(n0 + h * 128 + srow) * sK + kt * 64 + scol;
    _Float16* d = &Bsl[buf][h * 8192 + t * 8];
    gload_lds16(g, d);
    gload_lds16(g + 64 * sK, d + 4096);
  };
  auto RD_A = [&](int buf, int fr, int kk) -> f16x8 {
    const int row = wm * 64 + (fr & 3) * 16 + (fr >> 2) * 128 + rl;
    const int chunk = (kk * 4 + koff) ^ ((row >> 1) & 7);
    return *reinterpret_cast<const f16x8*>(&Asl[buf][row * 64 + chunk * 8]);
  };
  auto RD_B = [&](int buf, int fc, int kk) -> f16x8 {
    const int row = wn * 32 + (fc & 1) * 16 + (fc >> 1) * 128 + rl;
    const int chunk = (kk * 4 + koff) ^ ((row >> 1) & 7);
    return *reinterpret_cast<const f16x8*>(&Bsl[buf][row * 64 + chunk * 8]);
  };

#define PHASE(RH, CH, STAGE_STMT, CKPT_STMT) do {                              \
    f16x8 pa[4][2], pb[2][2];                                                  \
    _Pragma("unroll")                                                          \
    for (int i = 0; i < 4; ++i) {                                              \
      pa[i][0] = RD_A(cur, (RH) * 4 + i, 0);                                   \
      pa[i][1] = RD_A(cur, (RH) * 4 + i, 1);                                   \
    }                                                                          \
    _Pragma("unroll")                                                          \
    for (int j = 0; j < 2; ++j) {                                              \
      pb[j][0] = RD_B(cur, (CH) * 2 + j, 0);                                   \
      pb[j][1] = RD_B(cur, (CH) * 2 + j, 1);                                   \
    }                                                                          \
    STAGE_STMT;                                                                \
    __builtin_amdgcn_s_barrier();                                              \
    __builtin_amdgcn_s_setprio(1);                                             \
    _Pragma("unroll")                                                          \
    for (int i = 0; i < 4; ++i)                                                \
      _Pragma("unroll")                                                        \
      for (int j = 0; j < 2; ++j) {                                            \
        acc[(RH)*4+i][(CH)*2+j] = __builtin_amdgcn_mfma_f32_16x16x32_f16(      \
            pa[i][0], pb[j][0], acc[(RH)*4+i][(CH)*2+j], 0, 0, 0);             \
        acc[(RH)*4+i][(CH)*2+j] = __builtin_amdgcn_mfma_f32_16x16x32_f16(      \
            pa[i][1], pb[j][1], acc[(RH)*4+i][(CH)*2+j], 0, 0, 0);             \
      }                                                                        \
    __builtin_amdgcn_s_setprio(0);                                             \
    CKPT_STMT;                                                                 \
    __builtin_amdgcn_s_barrier();                                              \
  } while (0)

  const int nt = K >> 6;
  // prologue: K0 complete (8 loads) + K1.A0,B0 (4 loads); vmcnt(4) -> K0 landed
  STAGE_A(0, 0, 0); STAGE_A(0, 1, 0); STAGE_B(0, 0, 0); STAGE_B(0, 1, 0);
  STAGE_A(1, 0, 1); STAGE_B(1, 0, 1);
  asm volatile("s_waitcnt vmcnt(4)" ::: "memory");
  __builtin_amdgcn_s_barrier();

  for (int k = 0; k < nt; ++k) {
    const int cur = k & 1, nxt = cur ^ 1;
    PHASE(0, 0, { if (k + 1 < nt) STAGE_A(nxt, 1, k + 1); }, ((void)0));
    PHASE(0, 1, { if (k + 1 < nt) STAGE_B(nxt, 1, k + 1); }, ((void)0));
    PHASE(1, 0, { if (k + 2 < nt) STAGE_A(cur, 0, k + 2); }, ((void)0));
    PHASE(1, 1, { if (k + 2 < nt) STAGE_B(cur, 0, k + 2); },
          { if (k < nt - 2)       asm volatile("s_waitcnt vmcnt(4)" ::: "memory");
            else if (k == nt - 2) asm volatile("s_waitcnt vmcnt(0)" ::: "memory"); });
  }
#undef PHASE

  // epilogue: bias + relu + fp16 store. C/D: col=lane&15, row=(lane>>4)*4+reg (m89)
#pragma unroll
  for (int fc = 0; fc < 4; ++fc) {
    const int col = n0 + wn * 32 + (fc & 1) * 16 + (fc >> 1) * 128 + rl;
    const float bj = bias[col];
#pragma unroll
    for (int fr = 0; fr < 8; ++fr) {
      const int row0 = m0 + wm * 64 + (fr & 3) * 16 + (fr >> 2) * 128 + koff * 4;
#pragma unroll
      for (int r = 0; r < 4; ++r) {
        float v = acc[fr][fc][r] + bj;
        v = v > 0.f ? v : 0.f;
        C[(size_t)(row0 + r) * N + col] = (_Float16)v;
      }
    }
  }
}

// ---------------------------------------------------------------------------
// 128x128 depth-2 pipelined GEMM (GEMM2/3) — R3 kernel, unchanged.
// ---------------------------------------------------------------------------
__global__ __launch_bounds__(256) void gemm_bt_f16(
    const _Float16* __restrict__ A, const _Float16* __restrict__ Bt,
    const float* __restrict__ bias, _Float16* __restrict__ C,
    int M, int N, int K)
{
  __shared__ alignas(16) _Float16 lds[3 * 8192];
  const int t = threadIdx.x;
  const int lane = t & 63;
  const int wv = t >> 6;
  const int wm = wv >> 1, wn = wv & 1;
  const int m0 = blockIdx.x * 128, n0 = blockIdx.y * 128;

  const int srow = t >> 2;
  const int sc = (t & 3) ^ ((srow >> 1) & 3);
  const _Float16* Ag0 = A + (size_t)(m0 + srow) * K + sc * 8;
  const _Float16* Ag1 = A + (size_t)(m0 + 64 + srow) * K + sc * 8;
  const _Float16* Bg0 = Bt + (size_t)(n0 + srow) * K + sc * 8;
  const _Float16* Bg1 = Bt + (size_t)(n0 + 64 + srow) * K + sc * 8;
  const int sA0 = t * 8, sA1 = 2048 + t * 8;
  const int sB0 = 4096 + t * 8, sB1 = 6144 + t * 8;

  const int rl = lane & 15;
  const int koff = lane >> 4;

  f32x4 acc[4][4] = {};

  auto STAGE = [&](int bufo, int kt) {
    gload_lds16(Ag0 + kt, lds + bufo + sA0);
    gload_lds16(Ag1 + kt, lds + bufo + sA1);
    gload_lds16(Bg0 + kt, lds + bufo + sB0);
    gload_lds16(Bg1 + kt, lds + bufo + sB1);
  };

  auto COMPUTE = [&](int bufo) {
    f16x8 af[4], bf[4];
#pragma unroll
    for (int i = 0; i < 4; ++i) {
      const int ra = wm * 64 + i * 16 + rl;
      const int ca = koff ^ ((ra >> 1) & 3);
      af[i] = *reinterpret_cast<const f16x8*>(lds + bufo + ra * 32 + ca * 8);
      const int rb = wn * 64 + i * 16 + rl;
      const int cb = koff ^ ((rb >> 1) & 3);
      bf[i] = *reinterpret_cast<const f16x8*>(lds + bufo + 4096 + rb * 32 + cb * 8);
    }
    __builtin_amdgcn_s_setprio(1);
#pragma unroll
    for (int i = 0; i < 4; ++i)
#pragma unroll
      for (int j = 0; j < 4; ++j)
        acc[i][j] = __builtin_amdgcn_mfma_f32_16x16x32_f16(af[i], bf[j], acc[i][j], 0, 0, 0);
    __builtin_amdgcn_s_setprio(0);
  };

  int b0 = 0, b1 = 8192, b2 = 16384;
  STAGE(b0, 0);
  STAGE(b1, 32);
  asm volatile("s_waitcnt vmcnt(4)" ::: "memory");
  __builtin_amdgcn_s_barrier();

  const int nt = K / 32;
  int kst = 64;
  for (int tt = 0; tt < nt - 2; ++tt) {
    STAGE(b2, kst); kst += 32;
    COMPUTE(b0);
    asm volatile("s_waitcnt vmcnt(4)" ::: "memory");
    __builtin_amdgcn_s_barrier();
    const int tmp = b0; b0 = b1; b1 = b2; b2 = tmp;
  }
  COMPUTE(b0);
  asm volatile("s_waitcnt vmcnt(0)" ::: "memory");
  __builtin_amdgcn_s_barrier();
  COMPUTE(b1);

#pragma unroll
  for (int j = 0; j < 4; ++j) {
    const int col = n0 + wn * 64 + j * 16 + rl;
    const float bj = bias[col];
#pragma unroll
    for (int i = 0; i < 4; ++i) {
      const int row = m0 + wm * 64 + i * 16 + koff * 4;
#pragma unroll
      for (int r = 0; r < 4; ++r) {
        float v = acc[i][j][r] + bj;
        v = v > 0.f ? v : 0.f;
        C[(size_t)(row + r) * N + col] = (_Float16)v;
      }
    }
  }
}

// One wave per batch row: sk2, sk3, f4 partial dots + shuffle-reduce + readout.
__global__ __launch_bounds__(256) void k_final(
    const _Float16* __restrict__ h1, const _Float16* __restrict__ h2,
    const _Float16* __restrict__ h3,
    const int* __restrict__ d2, const float* __restrict__ wsk2, const float* __restrict__ bsk2,
    const int* __restrict__ d3, const float* __restrict__ wsk3, const float* __restrict__ bsk3,
    const float* __restrict__ W4, const float* __restrict__ b4,
    const float* __restrict__ Wro, const float* __restrict__ bro,
    float* __restrict__ out)
{
  const int gtid = blockIdx.x * 256 + threadIdx.x;
  const int b = gtid >> 6;
  const int lane = gtid & 63;
  const _Float16* r1 = h1 + (size_t)b * L2_SZ;
  const _Float16* r2 = h2 + (size_t)b * L3_SZ;
  const _Float16* r3 = h3 + (size_t)b * L4_SZ;
  float s2 = 0.f, s3 = 0.f, s4 = 0.f;
#pragma unroll
  for (int j = lane; j < ND2_SZ; j += 64) s2 += (float)r1[d2[j]] * wsk2[j];
#pragma unroll
  for (int j = lane; j < ND3_SZ; j += 64) s3 += (float)r2[d3[j]] * wsk3[j];
#pragma unroll
  for (int j = lane; j < L4_SZ; j += 64) s4 += (float)r3[j] * W4[j];
#pragma unroll
  for (int off = 32; off > 0; off >>= 1) {
    s2 += __shfl_xor(s2, off);
    s3 += __shfl_xor(s3, off);
    s4 += __shfl_xor(s4, off);
  }
  if (lane == 0) {
    const float v2 = fmaxf(s2 + bsk2[0], 0.f);
    const float v3 = fmaxf(s3 + bsk3[0], 0.f);
    const float v4 = fmaxf(s4 + b4[0], 0.f);
    out[b] = Wro[0] * v2 + Wro[1] * v3 + Wro[2] * v4 + bro[0];
  }
}

extern "C" void kernel_launch(void* const* d_in, const int* in_sizes, int n_in,
                              void* d_out, int out_size, void* d_ws, size_t ws_size,
                              hipStream_t stream) {
  const float* x    = (const float*)d_in[0];
  const int* in1    = (const int*)d_in[1];
  const int* out1   = (const int*)d_in[2];
  const float* w1   = (const float*)d_in[3];
  const float* b1   = (const float*)d_in[4];
  const int* in2    = (const int*)d_in[5];
  const int* out2   = (const int*)d_in[6];
  const float* w2   = (const float*)d_in[7];
  const float* b2   = (const float*)d_in[8];
  const int* d2     = (const int*)d_in[9];
  const float* wsk2 = (const float*)d_in[10];
  const float* bsk2 = (const float*)d_in[11];
  const int* in3    = (const int*)d_in[12];
  const int* out3   = (const int*)d_in[13];
  const float* w3   = (const float*)d_in[14];
  const float* b3   = (const float*)d_in[15];
  const int* d3     = (const int*)d_in[16];
  const float* wsk3 = (const float*)d_in[17];
  const float* bsk3 = (const float*)d_in[18];
  const float* W4   = (const float*)d_in[19];
  const float* b4   = (const float*)d_in[20];
  const float* Wro  = (const float*)d_in[21];
  const float* bro  = (const float*)d_in[22];
  float* out = (float*)d_out;

  char* ws = (char*)d_ws;
  _Float16* xh  = (_Float16*)(ws + 0);
  _Float16* W1h = (_Float16*)(ws + 67108864);
  _Float16* W2h = (_Float16*)(ws + 83886080);
  _Float16* W3h = (_Float16*)(ws + 88080384);
  _Float16* h1h = (_Float16*)(ws + 89128960);
  float*    Wf1 = (float*)   (ws + 122683392);
  _Float16* h2h = (_Float16*)(ws + 122683392);   // reuses Wf1 region after W1 convert
  _Float16* h3h = (_Float16*)(ws + 139460608);   // reuses Wf1 region after W1 convert
  float*    Wf2 = (float*)   (ws + 156237824);
  float*    Wf3 = (float*)   (ws + 164626432);

  // zero all three fp32 scatter scratches (contiguous 42MB)
  hipMemsetAsync(ws + 122683392, 0, 44040192, stream);

  // x -> fp16
  k_f32_to_f16<<<(B_SZ * L1_SZ / 8 + 255) / 256, 256, 0, stream>>>(x, xh, B_SZ * L1_SZ);

  // densify sparse weights (fp32 atomics handle duplicate edges), then convert fp16
  k_scatter<<<(NNZ1_SZ + 255) / 256, 256, 0, stream>>>(in1, out1, w1, NNZ1_SZ, Wf1, L1_SZ);
  k_scatter<<<(NNZ2_SZ + 255) / 256, 256, 0, stream>>>(in2, out2, w2, NNZ2_SZ, Wf2, L2_SZ);
  k_scatter<<<(NNZ3_SZ + 255) / 256, 256, 0, stream>>>(in3, out3, w3, NNZ3_SZ, Wf3, L3_SZ);
  k_f32_to_f16<<<(L2_SZ * L1_SZ / 8 + 255) / 256, 256, 0, stream>>>(Wf1, W1h, L2_SZ * L1_SZ);
  k_f32_to_f16<<<(L3_SZ * L2_SZ / 8 + 255) / 256, 256, 0, stream>>>(Wf2, W2h, L3_SZ * L2_SZ);
  k_f32_to_f16<<<(L4_SZ * L3_SZ / 8 + 255) / 256, 256, 0, stream>>>(Wf3, W3h, L4_SZ * L3_SZ);

  // GEMM chain: h1 = relu(x@W1^T+b1) [8-phase 256x256]; h2, h3 [128x128 pipeline]
  gemm256_f16<<<dim3(B_SZ / 256, L2_SZ / 256), 512, 0, stream>>>(xh, W1h, b1, h1h, B_SZ, L2_SZ, L1_SZ);
  gemm_bt_f16<<<dim3(B_SZ / 128, L3_SZ / 128), 256, 0, stream>>>(h1h, W2h, b2, h2h, B_SZ, L3_SZ, L2_SZ);
  gemm_bt_f16<<<dim3(B_SZ / 128, L4_SZ / 128), 256, 0, stream>>>(h2h, W3h, b3, h3h, B_SZ, L4_SZ, L3_SZ);

  // skips + fc4 + readout
  k_final<<<B_SZ * 64 / 256, 256, 0, stream>>>(h1h, h2h, h3h, d2, wsk2, bsk2,
                                               d3, wsk3, bsk3, W4, b4, Wro, bro, out);
}